// Round 5
// baseline (925.473 us; speedup 1.0000x reference)
//
#include <hip/hip_runtime.h>
#include <cstdint>
#include <cstddef>

#define BB 32
#define NN 24564
#define CC 81
#define CM1 80
#define KTOP 100
#define MAXDET 100
#define CBINS 28          // quarter-octave bins over score in (0.0078, 1]
#define CSHIFT 21
#define BASEBITS 0x3C000000u
#define CAP2 2048
#define TILE 128
#define NTILES ((NN + TILE - 1) / TILE)   // 192
#define HWORDS (CM1 * (CBINS / 2))        // 1120 packed u32 words

typedef unsigned long long ull;
typedef unsigned int uint;

// ---------------- pass 1: stage + exact softmax stats + proxy-binned LDS hist ----------------
// 256 threads, 128 rows: thread (r, half) owns classes [0,41) or [41,81) of row r.
__global__ __launch_bounds__(256) void softmax_hist_kernel(const float* __restrict__ conf,
                                                           uint* __restrict__ histg,
                                                           float2* __restrict__ mxs) {
    __shared__ __align__(16) float tile[TILE * CC];   // x, overwritten by e
    __shared__ float pmx[256];
    __shared__ float smx[TILE], ssum[TILE];
    __shared__ uint h[HWORDS];                        // 4480 B
    int tid = threadIdx.x;
    for (int i = tid; i < HWORDS; i += 256) h[i] = 0u;

    int b = blockIdx.x / NTILES, j = blockIdx.x % NTILES;
    int n0 = j * TILE;
    int cnt = NN - n0; if (cnt > TILE) cnt = TILE;

    const float4* src4 = reinterpret_cast<const float4*>(conf + ((size_t)b * NN + n0) * CC);
    float4* tile4 = reinterpret_cast<float4*>(tile);
    int tot4 = (cnt * CC) >> 2;
    for (int i = tid; i < tot4; i += 256) tile4[i] = src4[i];
    __syncthreads();

    int r = tid & 127, half = tid >> 7;
    bool act = (r < cnt);
    float* row = tile + r * CC;

    // parallel max (order-independent, exact)
    float m = -INFINITY;
    if (act) {
        if (half) { for (int c = 41; c < 81; ++c) m = fmaxf(m, row[c]); }
        else      { for (int c = 0;  c < 41; ++c) m = fmaxf(m, row[c]); }
    }
    pmx[tid] = m;
    __syncthreads();
    if (!half && act) smx[r] = fmaxf(pmx[r], pmx[r + 128]);
    __syncthreads();

    // e-phase: all lanes, overwrite x with e (exact op order)
    if (act) {
        float mx = smx[r];
        if (half) { for (int c = 41; c < 81; ++c) row[c] = expf(__fsub_rn(row[c], mx)); }
        else      { for (int c = 0;  c < 41; ++c) row[c] = expf(__fsub_rn(row[c], mx)); }
    }
    __syncthreads();

    // exact sequential sum (owner thread), persist (mx, s)
    if (!half && act) {
        float s = 0.f;
        for (int c = 0; c < CC; ++c) s = __fadd_rn(s, row[c]);
        ssum[r] = s;
        mxs[(size_t)b * NN + n0 + r] = make_float2(smx[r], s);
    }
    __syncthreads();

    // proxy scan + hist: all lanes; exact div only in the tiny ambiguity band
    if (act) {
        float s = ssum[r];
        float rcp = __builtin_amdgcn_rcpf(s);
        int cb = half ? 41 : 1, ce = half ? 81 : 41;
        for (int c = cb; c < ce; ++c) {
            float e = row[c];
            float p = __fmul_rn(e, rcp);
            if (p <= 0.0099990f) continue;            // certainly <= 0.01 (3e-7 rel err)
            uint bits;
            if (p >= 0.0100010f) bits = __float_as_uint(p);   // proxy bin (margin-covered)
            else {
                float sc = __fdiv_rn(e, s);
                if (!(sc > 0.01f)) continue;
                bits = __float_as_uint(sc);
            }
            uint bin = (bits - BASEBITS) >> CSHIFT;
            if (bin >= CBINS) bin = CBINS - 1;
            atomicAdd(&h[(c - 1) * (CBINS / 2) + (bin >> 1)], (bin & 1) ? 65536u : 1u);
        }
    }
    __syncthreads();
    uint* dst = histg + (size_t)blockIdx.x * HWORDS;
    for (int i = tid; i < HWORDS; i += 256) dst[i] = h[i];
}

// ---------------- pass 2: per-(b,c) sum packed partials, rank-100 cut with one-bin margin ----------------
__global__ __launch_bounds__(64) void cut_kernel(const uint* __restrict__ histg,
                                                 uint* __restrict__ cuts) {
    int bc = blockIdx.x;
    int b = bc / CM1, c = bc % CM1;
    __shared__ uint sh[CBINS];
    int t = threadIdx.x;
    if (t < CBINS / 2) {
        uint sum = 0;   // per-image counts <= 24564 fit u16: packed adds never carry
        for (int jj = 0; jj < NTILES; ++jj)
            sum += histg[(size_t)(b * NTILES + jj) * HWORDS + c * (CBINS / 2) + t];
        sh[2 * t]     = sum & 0xFFFFu;
        sh[2 * t + 1] = sum >> 16;
    }
    __syncthreads();
    if (t == 0) {
        uint total = 0;
        for (int i = 0; i < CBINS; ++i) total += sh[i];
        int Kt = (int)(total < KTOP ? total : KTOP);
        uint cutv = 0xFFFFFFFFu;
        if (Kt > 0) {
            uint cum = 0; int bb2 = 0;
            for (int i = CBINS - 1; i >= 0; --i) {
                cum += sh[i];
                if (cum >= (uint)Kt) { bb2 = i; break; }
            }
            uint cum_m = cum + ((bb2 > 0) ? sh[bb2 - 1] : 0u);
            uint cutbin;
            if (bb2 > 0 && cum_m <= CAP2) cutbin = (uint)(bb2 - 1);  // safety margin bin
            else if (cum <= CAP2)         cutbin = (uint)bb2;
            else                          cutbin = (uint)(bb2 + 1);
            cutv = BASEBITS + (cutbin << CSHIFT);
        }
        cuts[bc] = cutv;
    }
}

// ---------------- pass 3: element-parallel collect using persisted (mx,s) ----------------
__global__ __launch_bounds__(256) void collect_kernel(const float* __restrict__ conf,
                                                      const uint* __restrict__ cuts,
                                                      const float2* __restrict__ mxs,
                                                      ull* __restrict__ cand,
                                                      uint* __restrict__ ccnt) {
    __shared__ __align__(16) float tile[TILE * CC];
    __shared__ float smx[TILE], ssum[TILE];
    __shared__ uint lcut[CM1];
    __shared__ float pf[CM1];
    int tid = threadIdx.x;
    int b = blockIdx.x / NTILES, j = blockIdx.x % NTILES;
    int n0 = j * TILE;
    int cnt = NN - n0; if (cnt > TILE) cnt = TILE;

    if (tid < CM1) {
        uint cv = cuts[b * CM1 + tid];
        lcut[tid] = cv;
        pf[tid] = __fmul_rn(__uint_as_float(cv), 0.999f);  // NaN when empty -> compare false
    }
    if (tid < TILE && tid < cnt) {
        float2 v = mxs[(size_t)b * NN + n0 + tid];
        smx[tid] = v.x; ssum[tid] = v.y;
    }
    const float4* src4 = reinterpret_cast<const float4*>(conf + ((size_t)b * NN + n0) * CC);
    float4* tile4 = reinterpret_cast<float4*>(tile);
    int tot4 = (cnt * CC) >> 2;
    for (int i = tid; i < tot4; i += 256) tile4[i] = src4[i];
    __syncthreads();

    int r = tid & 127, half = tid >> 7;
    if (r < cnt) {
        float mx = smx[r], s = ssum[r];
        float rcp = __builtin_amdgcn_rcpf(s);
        const float* row = tile + r * CC;
        uint n = (uint)(n0 + r);
        int cb = half ? 41 : 1, ce = half ? 81 : 41;
        for (int c = cb; c < ce; ++c) {
            float e = expf(__fsub_rn(row[c], mx));
            float p = __fmul_rn(e, rcp);
            if (p > pf[c - 1]) {                       // ~1% pass rate
                float sc = __fdiv_rn(e, s);            // exact
                if (sc > 0.01f) {
                    uint bits = __float_as_uint(sc);
                    if (bits >= lcut[c - 1]) {
                        int bc = b * CM1 + (c - 1);
                        uint pp = atomicAdd(ccnt + bc, 1u);
                        if (pp < CAP2)
                            cand[(size_t)bc * CAP2 + pp] = (((ull)(~bits)) << 32) | n;
                    }
                }
            }
        }
    }
}

// ---------------- pass 4: per-(b,c) sort candidates + fused box decode + greedy NMS ----------------
__global__ __launch_bounds__(256) void nms_kernel(const ull* __restrict__ cand,
                                                  const uint* __restrict__ ccnt,
                                                  const float* __restrict__ loc,
                                                  const float* __restrict__ priors,
                                                  float* __restrict__ nms_scores,
                                                  float* __restrict__ nms_boxes) {
    int bc = blockIdx.x;
    int bimg = bc / CM1;
    __shared__ ull arr[CAP2];                 // 16 KB
    __shared__ float bx[KTOP][4];
    __shared__ float sv[KTOP];
    __shared__ ull mlo[KTOP], mhi[KTOP];
    __shared__ ull keeplo, keephi;

    int tid = threadIdx.x;
    int cc = (int)ccnt[bc]; if (cc > CAP2) cc = CAP2;
    int S = 1; while (S < cc) S <<= 1; if (S < 2) S = 2;
    const ull* crow = cand + (size_t)bc * CAP2;
    for (int i = tid; i < S; i += 256) arr[i] = (i < cc) ? crow[i] : ~0ull;
    __syncthreads();

    for (int k = 2; k <= S; k <<= 1) {
        for (int jj = k >> 1; jj > 0; jj >>= 1) {
            for (int i = tid; i < S; i += 256) {
                int ixj = i ^ jj;
                if (ixj > i) {
                    ull a = arr[i], b2 = arr[ixj];
                    bool up = ((i & k) == 0);
                    if ((a > b2) == up) { arr[i] = b2; arr[ixj] = a; }
                }
            }
            __syncthreads();
        }
    }

    if (tid < KTOP) {
        float val = 0.f; uint n = 0;
        if (tid < cc) {
            ull kk = arr[tid];
            val = __uint_as_float(~(uint)(kk >> 32));
            n = (uint)(kk & 0xFFFFFFFFu);
        }
        sv[tid] = val;
        float4 l = reinterpret_cast<const float4*>(loc)[(size_t)bimg * NN + n];
        float4 p = reinterpret_cast<const float4*>(priors)[n];
        float cx = __fadd_rn(__fmul_rn(__fmul_rn(l.x, 0.1f), p.z), p.x);
        float cy = __fadd_rn(__fmul_rn(__fmul_rn(l.y, 0.1f), p.w), p.y);
        float w  = __fmul_rn(expf(__fmul_rn(l.z, 0.2f)), p.z);
        float h  = __fmul_rn(expf(__fmul_rn(l.w, 0.2f)), p.w);
        bx[tid][0] = __fsub_rn(cx, __fmul_rn(w, 0.5f));
        bx[tid][1] = __fsub_rn(cy, __fmul_rn(h, 0.5f));
        bx[tid][2] = __fadd_rn(cx, __fmul_rn(w, 0.5f));
        bx[tid][3] = __fadd_rn(cy, __fmul_rn(h, 0.5f));
    }
    __syncthreads();

    if (tid < KTOP) {
        float x1 = bx[tid][0], y1 = bx[tid][1], x2 = bx[tid][2], y2 = bx[tid][3];
        float ai = __fmul_rn(fmaxf(__fsub_rn(x2, x1), 0.f), fmaxf(__fsub_rn(y2, y1), 0.f));
        ull lo = 0, hi = 0;
        for (int jj = 0; jj < KTOP; ++jj) {
            float jx1 = bx[jj][0], jy1 = bx[jj][1], jx2 = bx[jj][2], jy2 = bx[jj][3];
            float iw = fmaxf(__fsub_rn(fminf(x2, jx2), fmaxf(x1, jx1)), 0.f);
            float ih = fmaxf(__fsub_rn(fminf(y2, jy2), fmaxf(y1, jy1)), 0.f);
            float inter = __fmul_rn(iw, ih);
            float aj = __fmul_rn(fmaxf(__fsub_rn(jx2, jx1), 0.f), fmaxf(__fsub_rn(jy2, jy1), 0.f));
            float denom = __fadd_rn(__fsub_rn(__fadd_rn(ai, aj), inter), 1e-8f);
            float iou = __fdiv_rn(inter, denom);
            if (iou > 0.45f) { if (jj < 64) lo |= (1ull << jj); else hi |= (1ull << (jj - 64)); }
        }
        mlo[tid] = lo; mhi[tid] = hi;
    }
    __syncthreads();

    if (tid == 0) {
        ull klo = 0, khi = 0;
        for (int i = 0; i < KTOP; ++i) {
            ull sup = (mlo[i] & klo) | (mhi[i] & khi);
            bool kp = (sv[i] > 0.f) && (sup == 0ull);
            if (kp) { if (i < 64) klo |= (1ull << i); else khi |= (1ull << (i - 64)); }
        }
        keeplo = klo; keephi = khi;
    }
    __syncthreads();

    if (tid < KTOP) {
        bool kp = (tid < 64) ? ((keeplo >> tid) & 1ull) : ((keephi >> (tid - 64)) & 1ull);
        size_t obase = (size_t)bc * KTOP + tid;
        nms_scores[obase] = kp ? sv[tid] : 0.f;
        float4 o; o.x = bx[tid][0]; o.y = bx[tid][1]; o.z = bx[tid][2]; o.w = bx[tid][3];
        reinterpret_cast<float4*>(nms_boxes)[obase] = o;
    }
}

// ---------------- per-image final top-100 over 8000 candidates ----------------
__global__ __launch_bounds__(256) void final_topk_kernel(const float* __restrict__ nms_scores,
                                                         const float* __restrict__ nms_boxes,
                                                         float* __restrict__ out) {
    int b = blockIdx.x;
    __shared__ ull arr[8192];   // 64 KB
    int tid = threadIdx.x;
    const int NCAND = CM1 * KTOP;              // 8000
    const float* srow = nms_scores + (size_t)b * NCAND;
    for (int i = tid; i < 8192; i += 256) {
        ull key;
        if (i < NCAND) {
            float s = srow[i];
            uint bits = (s > 0.f) ? __float_as_uint(s) : 0u;
            key = (((ull)(~bits)) << 32) | (uint)i;
        } else key = ~0ull;
        arr[i] = key;
    }
    __syncthreads();
    for (int k = 2; k <= 8192; k <<= 1) {
        for (int jj = k >> 1; jj > 0; jj >>= 1) {
            for (int i = tid; i < 8192; i += 256) {
                int ixj = i ^ jj;
                if (ixj > i) {
                    ull a = arr[i], b2 = arr[ixj];
                    bool up = ((i & k) == 0);
                    if ((a > b2) == up) { arr[i] = b2; arr[ixj] = a; }
                }
            }
            __syncthreads();
        }
    }
    if (tid < MAXDET) {
        ull kk = arr[tid];
        uint hb = (uint)(kk >> 32);
        uint idx = (uint)(kk & 0xFFFFFFFFu);
        float val = __uint_as_float(~hb);
        float4 b4 = reinterpret_cast<const float4*>(nms_boxes)[(size_t)b * NCAND + idx];
        reinterpret_cast<float4*>(out)[(size_t)b * MAXDET + tid] = b4;
        out[BB * MAXDET * 4 + b * MAXDET + tid] = val;
        out[BB * MAXDET * 5 + b * MAXDET + tid] = (float)(idx / KTOP + 1);
    }
}

extern "C" void kernel_launch(void* const* d_in, const int* in_sizes, int n_in,
                              void* d_out, int out_size, void* d_ws, size_t ws_size,
                              hipStream_t stream) {
    const float* loc    = (const float*)d_in[0];
    const float* conf   = (const float*)d_in[1];
    const float* priors = (const float*)d_in[2];
    float* out = (float*)d_out;

    // workspace layout (16B-aligned chunks)
    char* ws = (char*)d_ws;
    float* nms_scores = (float*)ws;                                        // 1.02 MB
    float* nms_boxes  = nms_scores + (size_t)BB * CM1 * KTOP;              // 4.1 MB
    ull*   cand       = (ull*)(nms_boxes + (size_t)BB * CM1 * KTOP * 4);   // 41.9 MB
    float2* mxs       = (float2*)(cand + (size_t)BB * CM1 * CAP2);         // 6.3 MB
    uint*  histg      = (uint*)(mxs + (size_t)BB * NN);                    // 27.5 MB
    uint*  cuts       = histg + (size_t)BB * NTILES * HWORDS;              // 2560
    uint*  ccnt       = cuts + (size_t)BB * CM1;                           // 2560

    hipMemsetAsync(ccnt, 0, (size_t)BB * CM1 * sizeof(uint), stream);

    softmax_hist_kernel<<<BB * NTILES, 256, 0, stream>>>(conf, histg, mxs);
    cut_kernel<<<BB * CM1, 64, 0, stream>>>(histg, cuts);
    collect_kernel<<<BB * NTILES, 256, 0, stream>>>(conf, cuts, mxs, cand, ccnt);
    nms_kernel<<<BB * CM1, 256, 0, stream>>>(cand, ccnt, loc, priors, nms_scores, nms_boxes);
    final_topk_kernel<<<BB, 256, 0, stream>>>(nms_scores, nms_boxes, out);
}

// Round 6
// 707.316 us; speedup vs baseline: 1.3084x; 1.3084x over previous
//
#include <hip/hip_runtime.h>
#include <cstdint>
#include <cstddef>

#define BB 32
#define NN 24564
#define CC 81
#define CM1 80
#define KTOP 100
#define MAXDET 100
#define CBINS 28          // quarter-octave bins over score in (0.0078, 1]
#define CSHIFT 21
#define BASEBITS 0x3C000000u
#define CAP2 2048
#define BPI 96            // blocks per image, 256 rows each (96*256 >= 24564)
#define HWORDS (CM1 * (CBINS / 2))        // 1120 packed u32 words

typedef unsigned long long ull;
typedef unsigned int uint;
typedef float floatx4 __attribute__((ext_vector_type(4)));
typedef floatx4 uf4 __attribute__((aligned(4)));   // rows are only 4B-aligned

// ---------------- pass 1: register-resident rows, exact softmax stats + proxy LDS hist ----------------
// grid: BB*BPI blocks of 256; thread = one row. No tile staging, no mid-kernel barriers.
__global__ __launch_bounds__(256) void softmax_hist_kernel(const float* __restrict__ conf,
                                                           uint* __restrict__ histg,
                                                           float2* __restrict__ mxs) {
    __shared__ uint h[HWORDS];                        // 4480 B
    int tid = threadIdx.x;
    for (int i = tid; i < HWORDS; i += 256) h[i] = 0u;
    __syncthreads();

    int b = blockIdx.x / BPI, j = blockIdx.x % BPI;
    int n = j * 256 + tid;
    if (n < NN) {
        const float* row = conf + ((size_t)b * NN + n) * CC;
        const uf4* row4 = reinterpret_cast<const uf4*>(row);
        float r[CC];
        #pragma unroll
        for (int q = 0; q < 20; ++q) {
            floatx4 v = row4[q];
            r[4 * q] = v.x; r[4 * q + 1] = v.y; r[4 * q + 2] = v.z; r[4 * q + 3] = v.w;
        }
        r[80] = row[80];

        float mx = r[0];
        #pragma unroll
        for (int c = 1; c < CC; ++c) mx = fmaxf(mx, r[c]);   // max: order-independent, exact

        float s = 0.f;                                        // exact sequential sum, c = 0..80
        #pragma unroll
        for (int c = 0; c < CC; ++c) {
            r[c] = expf(__fsub_rn(r[c], mx));
            s = __fadd_rn(s, r[c]);
        }
        mxs[(size_t)b * NN + n] = make_float2(mx, s);

        float rcp = __builtin_amdgcn_rcpf(s);
        #pragma unroll
        for (int c = 1; c < CC; ++c) {
            float p = __fmul_rn(r[c], rcp);
            if (p <= 0.0099990f) continue;            // certainly <= 0.01 (rcp err ~1e-7)
            uint bits;
            if (p >= 0.0100010f) bits = __float_as_uint(p);   // proxy bin; cut margin covers +-1 bin
            else {
                float sc = __fdiv_rn(r[c], s);
                if (!(sc > 0.01f)) continue;
                bits = __float_as_uint(sc);
            }
            uint bin = (bits - BASEBITS) >> CSHIFT;
            if (bin >= CBINS) bin = CBINS - 1;
            atomicAdd(&h[(c - 1) * (CBINS / 2) + (bin >> 1)], (bin & 1) ? 65536u : 1u);
        }
    }
    __syncthreads();
    uint* dst = histg + (size_t)blockIdx.x * HWORDS;
    for (int i = tid; i < HWORDS; i += 256) dst[i] = h[i];
}

// ---------------- pass 2: per-(b,c) sum packed partials, rank-100 cut with one-bin margin ----------------
__global__ __launch_bounds__(64) void cut_kernel(const uint* __restrict__ histg,
                                                 uint* __restrict__ cuts) {
    int bc = blockIdx.x;
    int b = bc / CM1, c = bc % CM1;
    __shared__ uint sh[CBINS];
    int t = threadIdx.x;
    if (t < CBINS / 2) {
        uint sum = 0;   // halves <= 96*256 fit u16: packed adds never carry
        for (int jj = 0; jj < BPI; ++jj)
            sum += histg[(size_t)(b * BPI + jj) * HWORDS + c * (CBINS / 2) + t];
        sh[2 * t]     = sum & 0xFFFFu;
        sh[2 * t + 1] = sum >> 16;
    }
    __syncthreads();
    if (t == 0) {
        uint total = 0;
        for (int i = 0; i < CBINS; ++i) total += sh[i];
        int Kt = (int)(total < KTOP ? total : KTOP);
        uint cutv = 0xFFFFFFFFu;
        if (Kt > 0) {
            uint cum = 0; int bb2 = 0;
            for (int i = CBINS - 1; i >= 0; --i) {
                cum += sh[i];
                if (cum >= (uint)Kt) { bb2 = i; break; }
            }
            uint cum_m = cum + ((bb2 > 0) ? sh[bb2 - 1] : 0u);
            uint cutbin;
            if (bb2 > 0 && cum_m <= CAP2) cutbin = (uint)(bb2 - 1);  // margin bin (proxy-binning safety)
            else if (cum <= CAP2)         cutbin = (uint)bb2;
            else                          cutbin = (uint)(bb2 + 1);
            cutv = BASEBITS + (cutbin << CSHIFT);
        }
        cuts[bc] = cutv;
    }
}

// ---------------- pass 3: register rows + log-domain prefilter, exact collect >= cut ----------------
__global__ __launch_bounds__(256) void collect_kernel(const float* __restrict__ conf,
                                                      const uint* __restrict__ cuts,
                                                      const float2* __restrict__ mxs,
                                                      ull* __restrict__ cand,
                                                      uint* __restrict__ ccnt) {
    __shared__ uint lcut[CM1];
    __shared__ float lthr[CM1];
    int tid = threadIdx.x;
    int b = blockIdx.x / BPI, j = blockIdx.x % BPI;
    if (tid < CM1) {
        uint cv = cuts[b * CM1 + tid];
        lcut[tid] = cv;
        // log(cut*0.998): 2e-3 margin >> logf/expf/div rounding; NaN (empty class) -> filter false
        lthr[tid] = __logf(__uint_as_float(cv) * 0.998f);
    }
    __syncthreads();

    int n = j * 256 + tid;
    if (n < NN) {
        float2 ms = mxs[(size_t)b * NN + n];
        float mx = ms.x, s = ms.y;
        float t = mx + __logf(s);       // x > t + log(cut*0.998)  <=>  e/s > ~cut*0.998
        const float* row = conf + ((size_t)b * NN + n) * CC;
        const uf4* row4 = reinterpret_cast<const uf4*>(row);
        float r[CC];
        #pragma unroll
        for (int q = 0; q < 20; ++q) {
            floatx4 v = row4[q];
            r[4 * q] = v.x; r[4 * q + 1] = v.y; r[4 * q + 2] = v.z; r[4 * q + 3] = v.w;
        }
        r[80] = row[80];

        uint nn = (uint)n;
        #pragma unroll
        for (int c = 1; c < CC; ++c) {
            if (r[c] > t + lthr[c - 1]) {              // ~2% pass rate
                float e = expf(__fsub_rn(r[c], mx));   // exact recompute
                float sc = __fdiv_rn(e, s);            // exact score bits
                if (sc > 0.01f) {
                    uint bits = __float_as_uint(sc);
                    if (bits >= lcut[c - 1]) {
                        int bc = b * CM1 + (c - 1);
                        uint pp = atomicAdd(ccnt + bc, 1u);
                        if (pp < CAP2)
                            cand[(size_t)bc * CAP2 + pp] = (((ull)(~bits)) << 32) | nn;
                    }
                }
            }
        }
    }
}

// ---------------- pass 4: per-(b,c) sort candidates + fused box decode + greedy NMS ----------------
__global__ __launch_bounds__(256) void nms_kernel(const ull* __restrict__ cand,
                                                  const uint* __restrict__ ccnt,
                                                  const float* __restrict__ loc,
                                                  const float* __restrict__ priors,
                                                  float* __restrict__ nms_scores,
                                                  float* __restrict__ nms_boxes) {
    int bc = blockIdx.x;
    int bimg = bc / CM1;
    __shared__ ull arr[CAP2];                 // 16 KB
    __shared__ float bx[KTOP][4];
    __shared__ float sv[KTOP];
    __shared__ ull mlo[KTOP], mhi[KTOP];
    __shared__ ull keeplo, keephi;

    int tid = threadIdx.x;
    int cc = (int)ccnt[bc]; if (cc > CAP2) cc = CAP2;
    int S = 1; while (S < cc) S <<= 1; if (S < 2) S = 2;
    const ull* crow = cand + (size_t)bc * CAP2;
    for (int i = tid; i < S; i += 256) arr[i] = (i < cc) ? crow[i] : ~0ull;
    __syncthreads();

    for (int k = 2; k <= S; k <<= 1) {
        for (int jj = k >> 1; jj > 0; jj >>= 1) {
            for (int i = tid; i < S; i += 256) {
                int ixj = i ^ jj;
                if (ixj > i) {
                    ull a = arr[i], b2 = arr[ixj];
                    bool up = ((i & k) == 0);
                    if ((a > b2) == up) { arr[i] = b2; arr[ixj] = a; }
                }
            }
            __syncthreads();
        }
    }

    if (tid < KTOP) {
        float val = 0.f; uint n = 0;
        if (tid < cc) {
            ull kk = arr[tid];
            val = __uint_as_float(~(uint)(kk >> 32));
            n = (uint)(kk & 0xFFFFFFFFu);
        }
        sv[tid] = val;
        float4 l = reinterpret_cast<const float4*>(loc)[(size_t)bimg * NN + n];
        float4 p = reinterpret_cast<const float4*>(priors)[n];
        float cx = __fadd_rn(__fmul_rn(__fmul_rn(l.x, 0.1f), p.z), p.x);
        float cy = __fadd_rn(__fmul_rn(__fmul_rn(l.y, 0.1f), p.w), p.y);
        float w  = __fmul_rn(expf(__fmul_rn(l.z, 0.2f)), p.z);
        float h  = __fmul_rn(expf(__fmul_rn(l.w, 0.2f)), p.w);
        bx[tid][0] = __fsub_rn(cx, __fmul_rn(w, 0.5f));
        bx[tid][1] = __fsub_rn(cy, __fmul_rn(h, 0.5f));
        bx[tid][2] = __fadd_rn(cx, __fmul_rn(w, 0.5f));
        bx[tid][3] = __fadd_rn(cy, __fmul_rn(h, 0.5f));
    }
    __syncthreads();

    if (tid < KTOP) {
        float x1 = bx[tid][0], y1 = bx[tid][1], x2 = bx[tid][2], y2 = bx[tid][3];
        float ai = __fmul_rn(fmaxf(__fsub_rn(x2, x1), 0.f), fmaxf(__fsub_rn(y2, y1), 0.f));
        ull lo = 0, hi = 0;
        for (int jj = 0; jj < KTOP; ++jj) {
            float jx1 = bx[jj][0], jy1 = bx[jj][1], jx2 = bx[jj][2], jy2 = bx[jj][3];
            float iw = fmaxf(__fsub_rn(fminf(x2, jx2), fmaxf(x1, jx1)), 0.f);
            float ih = fmaxf(__fsub_rn(fminf(y2, jy2), fmaxf(y1, jy1)), 0.f);
            float inter = __fmul_rn(iw, ih);
            float aj = __fmul_rn(fmaxf(__fsub_rn(jx2, jx1), 0.f), fmaxf(__fsub_rn(jy2, jy1), 0.f));
            float denom = __fadd_rn(__fsub_rn(__fadd_rn(ai, aj), inter), 1e-8f);
            float iou = __fdiv_rn(inter, denom);
            if (iou > 0.45f) { if (jj < 64) lo |= (1ull << jj); else hi |= (1ull << (jj - 64)); }
        }
        mlo[tid] = lo; mhi[tid] = hi;
    }
    __syncthreads();

    if (tid == 0) {
        ull klo = 0, khi = 0;
        for (int i = 0; i < KTOP; ++i) {
            ull sup = (mlo[i] & klo) | (mhi[i] & khi);
            bool kp = (sv[i] > 0.f) && (sup == 0ull);
            if (kp) { if (i < 64) klo |= (1ull << i); else khi |= (1ull << (i - 64)); }
        }
        keeplo = klo; keephi = khi;
    }
    __syncthreads();

    if (tid < KTOP) {
        bool kp = (tid < 64) ? ((keeplo >> tid) & 1ull) : ((keephi >> (tid - 64)) & 1ull);
        size_t obase = (size_t)bc * KTOP + tid;
        nms_scores[obase] = kp ? sv[tid] : 0.f;
        float4 o; o.x = bx[tid][0]; o.y = bx[tid][1]; o.z = bx[tid][2]; o.w = bx[tid][3];
        reinterpret_cast<float4*>(nms_boxes)[obase] = o;
    }
}

// ---------------- per-image final top-100 over 8000 candidates ----------------
__global__ __launch_bounds__(256) void final_topk_kernel(const float* __restrict__ nms_scores,
                                                         const float* __restrict__ nms_boxes,
                                                         float* __restrict__ out) {
    int b = blockIdx.x;
    __shared__ ull arr[8192];   // 64 KB
    int tid = threadIdx.x;
    const int NCAND = CM1 * KTOP;              // 8000
    const float* srow = nms_scores + (size_t)b * NCAND;
    for (int i = tid; i < 8192; i += 256) {
        ull key;
        if (i < NCAND) {
            float s = srow[i];
            uint bits = (s > 0.f) ? __float_as_uint(s) : 0u;
            key = (((ull)(~bits)) << 32) | (uint)i;
        } else key = ~0ull;
        arr[i] = key;
    }
    __syncthreads();
    for (int k = 2; k <= 8192; k <<= 1) {
        for (int jj = k >> 1; jj > 0; jj >>= 1) {
            for (int i = tid; i < 8192; i += 256) {
                int ixj = i ^ jj;
                if (ixj > i) {
                    ull a = arr[i], b2 = arr[ixj];
                    bool up = ((i & k) == 0);
                    if ((a > b2) == up) { arr[i] = b2; arr[ixj] = a; }
                }
            }
            __syncthreads();
        }
    }
    if (tid < MAXDET) {
        ull kk = arr[tid];
        uint hb = (uint)(kk >> 32);
        uint idx = (uint)(kk & 0xFFFFFFFFu);
        float val = __uint_as_float(~hb);
        float4 b4 = reinterpret_cast<const float4*>(nms_boxes)[(size_t)b * NCAND + idx];
        reinterpret_cast<float4*>(out)[(size_t)b * MAXDET + tid] = b4;
        out[BB * MAXDET * 4 + b * MAXDET + tid] = val;
        out[BB * MAXDET * 5 + b * MAXDET + tid] = (float)(idx / KTOP + 1);
    }
}

extern "C" void kernel_launch(void* const* d_in, const int* in_sizes, int n_in,
                              void* d_out, int out_size, void* d_ws, size_t ws_size,
                              hipStream_t stream) {
    const float* loc    = (const float*)d_in[0];
    const float* conf   = (const float*)d_in[1];
    const float* priors = (const float*)d_in[2];
    float* out = (float*)d_out;

    // workspace layout (16B-aligned chunks)
    char* ws = (char*)d_ws;
    float* nms_scores = (float*)ws;                                        // 1.02 MB
    float* nms_boxes  = nms_scores + (size_t)BB * CM1 * KTOP;              // 4.1 MB
    ull*   cand       = (ull*)(nms_boxes + (size_t)BB * CM1 * KTOP * 4);   // 41.9 MB
    float2* mxs       = (float2*)(cand + (size_t)BB * CM1 * CAP2);         // 6.3 MB
    uint*  histg      = (uint*)(mxs + (size_t)BB * NN);                    // 13.8 MB
    uint*  cuts       = histg + (size_t)BB * BPI * HWORDS;                 // 2560
    uint*  ccnt       = cuts + (size_t)BB * CM1;                           // 2560

    hipMemsetAsync(ccnt, 0, (size_t)BB * CM1 * sizeof(uint), stream);

    softmax_hist_kernel<<<BB * BPI, 256, 0, stream>>>(conf, histg, mxs);
    cut_kernel<<<BB * CM1, 64, 0, stream>>>(histg, cuts);
    collect_kernel<<<BB * BPI, 256, 0, stream>>>(conf, cuts, mxs, cand, ccnt);
    nms_kernel<<<BB * CM1, 256, 0, stream>>>(cand, ccnt, loc, priors, nms_scores, nms_boxes);
    final_topk_kernel<<<BB, 256, 0, stream>>>(nms_scores, nms_boxes, out);
}

// Round 7
// 468.923 us; speedup vs baseline: 1.9736x; 1.5084x over previous
//
#include <hip/hip_runtime.h>
#include <cstdint>
#include <cstddef>

#define BB 32
#define NN 24564
#define CC 81
#define CM1 80
#define KTOP 100
#define MAXDET 100
#define CBINS 28          // quarter-octave bins over score in (0.0078, 1]
#define CSHIFT 21
#define BASEBITS 0x3C000000u
#define CAP2 2048
#define BPI 96            // blocks per image, 256 rows each (96*256 >= 24564)
#define HWORDS (CM1 * (CBINS / 2))        // 1120 packed u32 words
#define FCH 8             // final-topk chunks per image
#define FCHN 1000         // entries per chunk (10 classes)
#define FPAD 1024

typedef unsigned long long ull;
typedef unsigned int uint;
typedef float floatx4 __attribute__((ext_vector_type(4)));
typedef floatx4 uf4 __attribute__((aligned(4)));   // rows are only 4B-aligned

// ---------------- pass 1: register-resident rows, exact softmax stats + proxy LDS hist ----------------
__global__ __launch_bounds__(256) void softmax_hist_kernel(const float* __restrict__ conf,
                                                           uint* __restrict__ histg,
                                                           float2* __restrict__ mxs) {
    __shared__ uint h[HWORDS];                        // 4480 B
    int tid = threadIdx.x;
    for (int i = tid; i < HWORDS; i += 256) h[i] = 0u;
    __syncthreads();

    int b = blockIdx.x / BPI, j = blockIdx.x % BPI;
    int n = j * 256 + tid;
    if (n < NN) {
        const float* row = conf + ((size_t)b * NN + n) * CC;
        const uf4* row4 = reinterpret_cast<const uf4*>(row);
        float r[CC];
        #pragma unroll
        for (int q = 0; q < 20; ++q) {
            floatx4 v = row4[q];
            r[4 * q] = v.x; r[4 * q + 1] = v.y; r[4 * q + 2] = v.z; r[4 * q + 3] = v.w;
        }
        r[80] = row[80];

        float mx = r[0];
        #pragma unroll
        for (int c = 1; c < CC; ++c) mx = fmaxf(mx, r[c]);   // max: order-independent, exact

        float s = 0.f;                                        // exact sequential sum, c = 0..80
        #pragma unroll
        for (int c = 0; c < CC; ++c) {
            r[c] = expf(__fsub_rn(r[c], mx));
            s = __fadd_rn(s, r[c]);
        }
        mxs[(size_t)b * NN + n] = make_float2(mx, s);

        float rcp = __builtin_amdgcn_rcpf(s);
        #pragma unroll
        for (int c = 1; c < CC; ++c) {
            float p = __fmul_rn(r[c], rcp);
            if (p <= 0.0099990f) continue;            // certainly <= 0.01 (rcp err ~1e-7)
            uint bits;
            if (p >= 0.0100010f) bits = __float_as_uint(p);   // proxy bin; cut margin covers +-1 bin
            else {
                float sc = __fdiv_rn(r[c], s);
                if (!(sc > 0.01f)) continue;
                bits = __float_as_uint(sc);
            }
            uint bin = (bits - BASEBITS) >> CSHIFT;
            if (bin >= CBINS) bin = CBINS - 1;
            atomicAdd(&h[(c - 1) * (CBINS / 2) + (bin >> 1)], (bin & 1) ? 65536u : 1u);
        }
    }
    __syncthreads();
    uint* dst = histg + (size_t)blockIdx.x * HWORDS;
    for (int i = tid; i < HWORDS; i += 256) dst[i] = h[i];
}

// ---------------- pass 2: per-(b,c) sum packed partials, rank-100 cut with one-bin margin ----------------
__global__ __launch_bounds__(64) void cut_kernel(const uint* __restrict__ histg,
                                                 uint* __restrict__ cuts) {
    int bc = blockIdx.x;
    int b = bc / CM1, c = bc % CM1;
    __shared__ uint sh[CBINS];
    int t = threadIdx.x;
    if (t < CBINS / 2) {
        uint sum = 0;   // halves <= 96*256 fit u16: packed adds never carry
        for (int jj = 0; jj < BPI; ++jj)
            sum += histg[(size_t)(b * BPI + jj) * HWORDS + c * (CBINS / 2) + t];
        sh[2 * t]     = sum & 0xFFFFu;
        sh[2 * t + 1] = sum >> 16;
    }
    __syncthreads();
    if (t == 0) {
        uint total = 0;
        for (int i = 0; i < CBINS; ++i) total += sh[i];
        int Kt = (int)(total < KTOP ? total : KTOP);
        uint cutv = 0xFFFFFFFFu;
        if (Kt > 0) {
            uint cum = 0; int bb2 = 0;
            for (int i = CBINS - 1; i >= 0; --i) {
                cum += sh[i];
                if (cum >= (uint)Kt) { bb2 = i; break; }
            }
            uint cum_m = cum + ((bb2 > 0) ? sh[bb2 - 1] : 0u);
            uint cutbin;
            if (bb2 > 0 && cum_m <= CAP2) cutbin = (uint)(bb2 - 1);  // margin bin (proxy-binning safety)
            else if (cum <= CAP2)         cutbin = (uint)bb2;
            else                          cutbin = (uint)(bb2 + 1);
            cutv = BASEBITS + (cutbin << CSHIFT);
        }
        cuts[bc] = cutv;
    }
}

// ---------------- pass 3: register rows + log-domain prefilter, exact collect >= cut ----------------
__global__ __launch_bounds__(256) void collect_kernel(const float* __restrict__ conf,
                                                      const uint* __restrict__ cuts,
                                                      const float2* __restrict__ mxs,
                                                      ull* __restrict__ cand,
                                                      uint* __restrict__ ccnt) {
    __shared__ uint lcut[CM1];
    __shared__ float lthr[CM1];
    int tid = threadIdx.x;
    int b = blockIdx.x / BPI, j = blockIdx.x % BPI;
    if (tid < CM1) {
        uint cv = cuts[b * CM1 + tid];
        lcut[tid] = cv;
        // log(cut*0.998): 2e-3 margin >> logf/expf/div rounding; NaN (empty class) -> filter false
        lthr[tid] = __logf(__uint_as_float(cv) * 0.998f);
    }
    __syncthreads();

    int n = j * 256 + tid;
    if (n < NN) {
        float2 ms = mxs[(size_t)b * NN + n];
        float mx = ms.x, s = ms.y;
        float t = mx + __logf(s);       // x > t + log(cut*0.998)  <=>  e/s > ~cut*0.998
        const float* row = conf + ((size_t)b * NN + n) * CC;
        const uf4* row4 = reinterpret_cast<const uf4*>(row);
        float r[CC];
        #pragma unroll
        for (int q = 0; q < 20; ++q) {
            floatx4 v = row4[q];
            r[4 * q] = v.x; r[4 * q + 1] = v.y; r[4 * q + 2] = v.z; r[4 * q + 3] = v.w;
        }
        r[80] = row[80];

        uint nn = (uint)n;
        #pragma unroll
        for (int c = 1; c < CC; ++c) {
            if (r[c] > t + lthr[c - 1]) {              // ~2% pass rate
                float e = expf(__fsub_rn(r[c], mx));   // exact recompute
                float sc = __fdiv_rn(e, s);            // exact score bits
                if (sc > 0.01f) {
                    uint bits = __float_as_uint(sc);
                    if (bits >= lcut[c - 1]) {
                        int bc = b * CM1 + (c - 1);
                        uint pp = atomicAdd(ccnt + bc, 1u);
                        if (pp < CAP2)
                            cand[(size_t)bc * CAP2 + pp] = (((ull)(~bits)) << 32) | nn;
                    }
                }
            }
        }
    }
}

// ---------------- pass 4: per-(b,c) sort candidates + fused box decode + greedy NMS ----------------
__global__ __launch_bounds__(256) void nms_kernel(const ull* __restrict__ cand,
                                                  const uint* __restrict__ ccnt,
                                                  const float* __restrict__ loc,
                                                  const float* __restrict__ priors,
                                                  float* __restrict__ nms_scores,
                                                  float* __restrict__ nms_boxes) {
    int bc = blockIdx.x;
    int bimg = bc / CM1;
    __shared__ ull arr[CAP2];                 // 16 KB
    __shared__ float bx[KTOP][4];
    __shared__ float sv[KTOP];
    __shared__ ull mlo[KTOP], mhi[KTOP];
    __shared__ ull keeplo, keephi;

    int tid = threadIdx.x;
    int cc = (int)ccnt[bc]; if (cc > CAP2) cc = CAP2;
    int S = 1; while (S < cc) S <<= 1; if (S < 2) S = 2;
    const ull* crow = cand + (size_t)bc * CAP2;
    for (int i = tid; i < S; i += 256) arr[i] = (i < cc) ? crow[i] : ~0ull;
    __syncthreads();

    for (int k = 2; k <= S; k <<= 1) {
        for (int jj = k >> 1; jj > 0; jj >>= 1) {
            for (int i = tid; i < S; i += 256) {
                int ixj = i ^ jj;
                if (ixj > i) {
                    ull a = arr[i], b2 = arr[ixj];
                    bool up = ((i & k) == 0);
                    if ((a > b2) == up) { arr[i] = b2; arr[ixj] = a; }
                }
            }
            __syncthreads();
        }
    }

    if (tid < KTOP) {
        float val = 0.f; uint n = 0;
        if (tid < cc) {
            ull kk = arr[tid];
            val = __uint_as_float(~(uint)(kk >> 32));
            n = (uint)(kk & 0xFFFFFFFFu);
        }
        sv[tid] = val;
        float4 l = reinterpret_cast<const float4*>(loc)[(size_t)bimg * NN + n];
        float4 p = reinterpret_cast<const float4*>(priors)[n];
        float cx = __fadd_rn(__fmul_rn(__fmul_rn(l.x, 0.1f), p.z), p.x);
        float cy = __fadd_rn(__fmul_rn(__fmul_rn(l.y, 0.1f), p.w), p.y);
        float w  = __fmul_rn(expf(__fmul_rn(l.z, 0.2f)), p.z);
        float h  = __fmul_rn(expf(__fmul_rn(l.w, 0.2f)), p.w);
        bx[tid][0] = __fsub_rn(cx, __fmul_rn(w, 0.5f));
        bx[tid][1] = __fsub_rn(cy, __fmul_rn(h, 0.5f));
        bx[tid][2] = __fadd_rn(cx, __fmul_rn(w, 0.5f));
        bx[tid][3] = __fadd_rn(cy, __fmul_rn(h, 0.5f));
    }
    __syncthreads();

    if (tid < KTOP) {
        float x1 = bx[tid][0], y1 = bx[tid][1], x2 = bx[tid][2], y2 = bx[tid][3];
        float ai = __fmul_rn(fmaxf(__fsub_rn(x2, x1), 0.f), fmaxf(__fsub_rn(y2, y1), 0.f));
        ull lo = 0, hi = 0;
        for (int jj = 0; jj < KTOP; ++jj) {
            float jx1 = bx[jj][0], jy1 = bx[jj][1], jx2 = bx[jj][2], jy2 = bx[jj][3];
            float iw = fmaxf(__fsub_rn(fminf(x2, jx2), fmaxf(x1, jx1)), 0.f);
            float ih = fmaxf(__fsub_rn(fminf(y2, jy2), fmaxf(y1, jy1)), 0.f);
            float inter = __fmul_rn(iw, ih);
            float aj = __fmul_rn(fmaxf(__fsub_rn(jx2, jx1), 0.f), fmaxf(__fsub_rn(jy2, jy1), 0.f));
            float denom = __fadd_rn(__fsub_rn(__fadd_rn(ai, aj), inter), 1e-8f);
            float iou = __fdiv_rn(inter, denom);
            if (iou > 0.45f) { if (jj < 64) lo |= (1ull << jj); else hi |= (1ull << (jj - 64)); }
        }
        mlo[tid] = lo; mhi[tid] = hi;
    }
    __syncthreads();

    if (tid == 0) {
        ull klo = 0, khi = 0;
        for (int i = 0; i < KTOP; ++i) {
            ull sup = (mlo[i] & klo) | (mhi[i] & khi);
            bool kp = (sv[i] > 0.f) && (sup == 0ull);
            if (kp) { if (i < 64) klo |= (1ull << i); else khi |= (1ull << (i - 64)); }
        }
        keeplo = klo; keephi = khi;
    }
    __syncthreads();

    if (tid < KTOP) {
        bool kp = (tid < 64) ? ((keeplo >> tid) & 1ull) : ((keephi >> (tid - 64)) & 1ull);
        size_t obase = (size_t)bc * KTOP + tid;
        nms_scores[obase] = kp ? sv[tid] : 0.f;
        float4 o; o.x = bx[tid][0]; o.y = bx[tid][1]; o.z = bx[tid][2]; o.w = bx[tid][3];
        reinterpret_cast<float4*>(nms_boxes)[obase] = o;
    }
}

// ---------------- final top-100, stage A: per-(image,chunk) top-100 of 1000 ----------------
__global__ __launch_bounds__(256) void final_partial_kernel(const float* __restrict__ nms_scores,
                                                            ull* __restrict__ fkeys) {
    int blk = blockIdx.x;             // b*FCH + ch
    int b = blk / FCH, ch = blk % FCH;
    __shared__ ull arr[FPAD];         // 8 KB
    int tid = threadIdx.x;
    const float* srow = nms_scores + (size_t)b * (CM1 * KTOP) + ch * FCHN;
    for (int i = tid; i < FPAD; i += 256) {
        ull key;
        if (i < FCHN) {
            float s = srow[i];
            uint bits = (s > 0.f) ? __float_as_uint(s) : 0u;
            key = (((ull)(~bits)) << 32) | (uint)(ch * FCHN + i);   // global per-image idx
        } else key = ~0ull;
        arr[i] = key;
    }
    __syncthreads();
    for (int k = 2; k <= FPAD; k <<= 1) {
        for (int jj = k >> 1; jj > 0; jj >>= 1) {
            for (int i = tid; i < FPAD; i += 256) {
                int ixj = i ^ jj;
                if (ixj > i) {
                    ull a = arr[i], b2 = arr[ixj];
                    bool up = ((i & k) == 0);
                    if ((a > b2) == up) { arr[i] = b2; arr[ixj] = a; }
                }
            }
            __syncthreads();
        }
    }
    if (tid < KTOP)
        fkeys[(size_t)b * (FCH * KTOP) + ch * KTOP + tid] = arr[tid];
}

// ---------------- final top-100, stage B: merge 8x100 -> exact top-100, gather ----------------
__global__ __launch_bounds__(256) void final_merge_kernel(const ull* __restrict__ fkeys,
                                                          const float* __restrict__ nms_boxes,
                                                          float* __restrict__ out) {
    int b = blockIdx.x;
    __shared__ ull arr[FPAD];         // 8 KB
    int tid = threadIdx.x;
    const ull* krow = fkeys + (size_t)b * (FCH * KTOP);
    for (int i = tid; i < FPAD; i += 256)
        arr[i] = (i < FCH * KTOP) ? krow[i] : ~0ull;
    __syncthreads();
    for (int k = 2; k <= FPAD; k <<= 1) {
        for (int jj = k >> 1; jj > 0; jj >>= 1) {
            for (int i = tid; i < FPAD; i += 256) {
                int ixj = i ^ jj;
                if (ixj > i) {
                    ull a = arr[i], b2 = arr[ixj];
                    bool up = ((i & k) == 0);
                    if ((a > b2) == up) { arr[i] = b2; arr[ixj] = a; }
                }
            }
            __syncthreads();
        }
    }
    if (tid < MAXDET) {
        ull kk = arr[tid];
        uint hb = (uint)(kk >> 32);
        uint idx = (uint)(kk & 0xFFFFFFFFu);
        float val = __uint_as_float(~hb);     // zeros decode to 0.0f
        float4 b4 = reinterpret_cast<const float4*>(nms_boxes)[(size_t)b * (CM1 * KTOP) + idx];
        reinterpret_cast<float4*>(out)[(size_t)b * MAXDET + tid] = b4;
        out[BB * MAXDET * 4 + b * MAXDET + tid] = val;
        out[BB * MAXDET * 5 + b * MAXDET + tid] = (float)(idx / KTOP + 1);
    }
}

extern "C" void kernel_launch(void* const* d_in, const int* in_sizes, int n_in,
                              void* d_out, int out_size, void* d_ws, size_t ws_size,
                              hipStream_t stream) {
    const float* loc    = (const float*)d_in[0];
    const float* conf   = (const float*)d_in[1];
    const float* priors = (const float*)d_in[2];
    float* out = (float*)d_out;

    // workspace layout (16B-aligned chunks)
    char* ws = (char*)d_ws;
    float* nms_scores = (float*)ws;                                        // 1.02 MB
    float* nms_boxes  = nms_scores + (size_t)BB * CM1 * KTOP;              // 4.1 MB
    ull*   cand       = (ull*)(nms_boxes + (size_t)BB * CM1 * KTOP * 4);   // 41.9 MB
    float2* mxs       = (float2*)(cand + (size_t)BB * CM1 * CAP2);         // 6.3 MB
    ull*   fkeys      = (ull*)(mxs + (size_t)BB * NN);                     // 32*800*8 = 0.2 MB
    uint*  histg      = (uint*)(fkeys + (size_t)BB * FCH * KTOP);          // 13.8 MB
    uint*  cuts       = histg + (size_t)BB * BPI * HWORDS;                 // 2560
    uint*  ccnt       = cuts + (size_t)BB * CM1;                           // 2560

    hipMemsetAsync(ccnt, 0, (size_t)BB * CM1 * sizeof(uint), stream);

    softmax_hist_kernel<<<BB * BPI, 256, 0, stream>>>(conf, histg, mxs);
    cut_kernel<<<BB * CM1, 64, 0, stream>>>(histg, cuts);
    collect_kernel<<<BB * BPI, 256, 0, stream>>>(conf, cuts, mxs, cand, ccnt);
    nms_kernel<<<BB * CM1, 256, 0, stream>>>(cand, ccnt, loc, priors, nms_scores, nms_boxes);
    final_partial_kernel<<<BB * FCH, 256, 0, stream>>>(nms_scores, fkeys);
    final_merge_kernel<<<BB, 256, 0, stream>>>(fkeys, nms_boxes, out);
}